// Round 1
// baseline (678.339 us; speedup 1.0000x reference)
//
#include <hip/hip_runtime.h>

#define CODEBOOK 131072
#define DIM 1024
#define ROWS_PER_WAVE 8
#define WAVES_PER_BLOCK 4
#define ROWS_PER_BLOCK (ROWS_PER_WAVE * WAVES_PER_BLOCK)   // 32
#define NB (CODEBOOK / ROWS_PER_BLOCK)                     // 4096 blocks

__device__ __forceinline__ unsigned long long shfl_down_u64(unsigned long long v, int off) {
    unsigned lo = (unsigned)(v & 0xFFFFFFFFu);
    unsigned hi = (unsigned)(v >> 32);
    lo = __shfl_down(lo, off, 64);
    hi = __shfl_down(hi, off, 64);
    return ((unsigned long long)hi << 32) | (unsigned long long)lo;
}

// Pack a float into an order-preserving u32 key (monotone increasing).
__device__ __forceinline__ unsigned float_key(float f) {
    unsigned u = __float_as_uint(f);
    return (u & 0x80000000u) ? ~u : (u | 0x80000000u);
}

// Kernel 1: dot(W[row], z) for all rows; per-block argmax partial.
// One wave per row stream; lane l loads Wrow[j*64+l] as float4 (coalesced 1KB/instr).
__global__ __launch_bounds__(256) void vq_dot_kernel(const float* __restrict__ z,
                                                     const float* __restrict__ W,
                                                     unsigned long long* __restrict__ partials) {
    const int lane = threadIdx.x & 63;
    const int wave = threadIdx.x >> 6;

    // z is identical for every row: preload this lane's 16 elements into registers.
    const float4* z4 = (const float4*)z;
    float4 zr[4];
#pragma unroll
    for (int j = 0; j < 4; ++j) zr[j] = z4[j * 64 + lane];

    const int row0 = blockIdx.x * ROWS_PER_BLOCK + wave * ROWS_PER_WAVE;
    unsigned long long best = 0ULL;  // below any real key (dots in [-1,1])

#pragma unroll
    for (int r = 0; r < ROWS_PER_WAVE; ++r) {
        const int row = row0 + r;
        const float4* Wrow = (const float4*)(W + (size_t)row * DIM);
        float4 acc = make_float4(0.f, 0.f, 0.f, 0.f);
#pragma unroll
        for (int j = 0; j < 4; ++j) {
            float4 w = Wrow[j * 64 + lane];
            acc.x = fmaf(w.x, zr[j].x, acc.x);
            acc.y = fmaf(w.y, zr[j].y, acc.y);
            acc.z = fmaf(w.z, zr[j].z, acc.z);
            acc.w = fmaf(w.w, zr[j].w, acc.w);
        }
        float dot = (acc.x + acc.y) + (acc.z + acc.w);
#pragma unroll
        for (int off = 32; off > 0; off >>= 1)
            dot += __shfl_down(dot, off, 64);
        if (lane == 0) {
            // key in high 32 bits; ~row in low 32 so equal keys prefer LOWER row
            unsigned long long p =
                ((unsigned long long)float_key(dot) << 32) |
                (unsigned long long)(~(unsigned)row);
            if (p > best) best = p;
        }
    }

    __shared__ unsigned long long sbest[WAVES_PER_BLOCK];
    if (lane == 0) sbest[wave] = best;
    __syncthreads();
    if (threadIdx.x == 0) {
        unsigned long long b = sbest[0];
#pragma unroll
        for (int i = 1; i < WAVES_PER_BLOCK; ++i)
            if (sbest[i] > b) b = sbest[i];
        partials[blockIdx.x] = b;
    }
}

// Kernel 2: reduce 4096 partials -> index; emit quantized_st, index, loss.
__global__ __launch_bounds__(256) void vq_finalize(const float* __restrict__ z,
                                                   const float* __restrict__ W,
                                                   const unsigned long long* __restrict__ partials,
                                                   float* __restrict__ out) {
    __shared__ unsigned long long swin[WAVES_PER_BLOCK];
    __shared__ float ssum[WAVES_PER_BLOCK];
    const int tid = threadIdx.x;
    const int lane = tid & 63;
    const int wave = tid >> 6;

    unsigned long long best = 0ULL;
    for (int i = tid; i < NB; i += 256) {
        unsigned long long p = partials[i];
        if (p > best) best = p;
    }
#pragma unroll
    for (int off = 32; off > 0; off >>= 1) {
        unsigned long long o = shfl_down_u64(best, off);
        if (o > best) best = o;
    }
    if (lane == 0) swin[wave] = best;
    __syncthreads();
    if (tid == 0) {
        unsigned long long b = swin[0];
#pragma unroll
        for (int i = 1; i < WAVES_PER_BLOCK; ++i)
            if (swin[i] > b) b = swin[i];
        swin[0] = b;
    }
    __syncthreads();

    const unsigned idx = ~(unsigned)(swin[0] & 0xFFFFFFFFu);
    const float4* Wrow = (const float4*)(W + (size_t)idx * DIM);
    const float4* z4 = (const float4*)z;

    float4 q = Wrow[tid];       // 256 threads x float4 = 1024 elements
    float4 zv = z4[tid];

    // straight-through estimator arithmetic, matching the reference exactly:
    float4 st;
    st.x = zv.x + (q.x - zv.x);
    st.y = zv.y + (q.y - zv.y);
    st.z = zv.z + (q.z - zv.z);
    st.w = zv.w + (q.w - zv.w);
    ((float4*)out)[tid] = st;

    float dx = zv.x - q.x, dy = zv.y - q.y, dz = zv.z - q.z, dw = zv.w - q.w;
    float s = dx * dx + dy * dy + dz * dz + dw * dw;
#pragma unroll
    for (int off = 32; off > 0; off >>= 1)
        s += __shfl_down(s, off, 64);
    if (lane == 0) ssum[wave] = s;
    __syncthreads();
    if (tid == 0) {
        float tot = ssum[0] + ssum[1] + ssum[2] + ssum[3];
        out[DIM] = (float)idx;                          // index (exact in fp32)
        out[DIM + 1] = 0.25f * (tot / (float)DIM);      // commitment loss
    }
}

extern "C" void kernel_launch(void* const* d_in, const int* in_sizes, int n_in,
                              void* d_out, int out_size, void* d_ws, size_t ws_size,
                              hipStream_t stream) {
    const float* z = (const float*)d_in[0];
    const float* W = (const float*)d_in[1];
    float* out = (float*)d_out;
    unsigned long long* partials = (unsigned long long*)d_ws;  // 4096 * 8 B = 32 KB

    vq_dot_kernel<<<NB, 256, 0, stream>>>(z, W, partials);
    vq_finalize<<<1, 256, 0, stream>>>(z, W, partials, out);
}